// Round 13
// baseline (73.619 us; speedup 1.0000x reference)
//
#include <hip/hip_runtime.h>

namespace {

constexpr int kB = 256;
constexpr int kS = 512;
constexpr int CHUNK  = 30;                        // useful frames per wave (32 lane-pairs, 2 overlap)
constexpr int NCHUNK = (kS + CHUNK - 1) / CHUNK;  // 18
constexpr int NSLOT  = 64;
constexpr int LROW   = 38;                        // LDS row stride (floats)
constexpr int LWAVE  = 64 * LROW;                 // per-WG LDS floats (9728 B)

// lambda / count constants as inline literals (zero register cost).
constexpr float BSf   = 131072.f;                 // kB*kS
constexpr float K_R1  = 5.0f / (2.f * BSf * 3.f);
constexpr float K_R2  = 5.0f / (2.f * BSf * 6.f);
constexpr float K_ROT = 1.0f / (2.f * BSf * 120.f);
constexpr float K_POS = 2.0f / (2.f * BSf * 66.f);
constexpr float K_VEL = 1.0f / (2.f * 256.f * 511.f * 66.f);
constexpr float K_SMO = 0.5f / (2.f * 256.f * 510.f * 66.f);
constexpr float K_FLO = 2.0f / (2.f * BSf * 2.f);
constexpr float K_CON = 2.0f / (256.f * 511.f * 2.f);   // even lanes only (no 2x)
constexpr float K_TIL = 1.0f / (2.f * BSf * 3.f);

__device__ __forceinline__ void cont6d(const float a[6], float R[3][3]) {
    float n1 = sqrtf(a[0]*a[0] + a[1]*a[1] + a[2]*a[2]);
    float i1 = 1.0f / fmaxf(n1, 1e-12f);
    float b1x = a[0]*i1, b1y = a[1]*i1, b1z = a[2]*i1;
    float dp  = b1x*a[3] + b1y*a[4] + b1z*a[5];
    float ux = a[3] - b1x*dp, uy = a[4] - b1y*dp, uz = a[5] - b1z*dp;
    float n2 = sqrtf(ux*ux + uy*uy + uz*uz);
    float i2 = 1.0f / fmaxf(n2, 1e-12f);
    float b2x = ux*i2, b2y = uy*i2, b2z = uz*i2;
    R[0][0] = b1x; R[1][0] = b1y; R[2][0] = b1z;
    R[0][1] = b2x; R[1][1] = b2y; R[2][1] = b2z;
    R[0][2] = b1y*b2z - b1z*b2y;
    R[1][2] = b1z*b2x - b1x*b2z;
    R[2][2] = b1x*b2y - b1y*b2x;
}

// Fused coalesced global -> LDS stage, runtime FB (r9-proven form).
template<int C2>
__device__ __forceinline__ void stage(const float* __restrict__ pred,
                                      const float* __restrict__ targ,
                                      size_t rowbase, int s0, int FB,
                                      float* __restrict__ ldsw, int lane) {
    constexpr int V = 32 * C2;           // float2 elements per tensor
    constexpr int R = (2 * V) / 64;      // C2 in {18,12} -> R in {18,12}
    float2 st[18];
    #pragma unroll
    for (int r = 0; r < R; ++r) {
        int u = r * 64 + lane;
        int par2 = (u >= V) ? 1 : 0;
        int uu = u - par2 * V;
        int f = uu / C2;
        int c = uu - f * C2;
        int sf = s0 + f; sf = (sf < kS) ? sf : (kS - 1);
        const float* tp = par2 ? targ : pred;
        st[r] = *reinterpret_cast<const float2*>(tp + (rowbase + (size_t)sf) * 132 + FB + 2 * c);
    }
    #pragma unroll
    for (int r = 0; r < R; ++r) {
        int u = r * 64 + lane;
        int par2 = (u >= V) ? 1 : 0;
        int uu = u - par2 * V;
        int f = uu / C2;
        int c = uu - f * C2;
        *reinterpret_cast<float2*>(ldsw + (2 * f + par2) * LROW + 2 * c) = st[r];
    }
}

__device__ __forceinline__ void read6(const float* __restrict__ row, int jj, float a[6]) {
    const float2* q = reinterpret_cast<const float2*>(row + 6 * jj);
    float2 x = q[0], y = q[1], z = q[2];
    a[0]=x.x; a[1]=x.y; a[2]=y.x; a[3]=y.y; a[4]=z.x; a[5]=z.y;
}

__device__ __forceinline__ void cp9(const float S[3][3], float D[3][3]) {
    #pragma unroll
    for (int r = 0; r < 3; ++r)
        #pragma unroll
        for (int c = 0; c < 3; ++c) D[r][c] = S[r][c];
}

// Rolled FK loop: joint traversal 2..21 IS joint-id order. Parent = previous
// joint except restores {2,14,19}->R1, {6,10}->R3; one save (j3 -> R3).
// All branching is wave-uniform (loop counter only) -> s_cbranch, no
// divergence. Code size ~5 KB (vs ~45 KB unrolled) -> fits 32 KiB L1I.
__global__ __launch_bounds__(64)
void motion_loss_kernel(const float* __restrict__ pred,
                        const float* __restrict__ targ,
                        const float* __restrict__ offs,
                        float* __restrict__ acc)
{
    __shared__ float lds[LWAVE];

    const int lane = threadIdx.x;
    const int fid  = lane >> 1;         // frame-in-chunk 0..31
    const int par  = lane & 1;          // 0 = pred, 1 = targ

    const int cg    = blockIdx.x;                 // chunk id, 0..4607
    const int b     = cg / NCHUNK;
    const int chunk = cg - b * NCHUNK;
    const int s0    = chunk * CHUNK;
    const int s     = s0 + fid;
    const size_t rowbase = (size_t)b * kS;

    const float wf = (fid < CHUNK && s     < kS) ? 1.f : 0.f;
    const float wv = (fid < CHUNK && s + 1 < kS) ? 1.f : 0.f;
    const float wa = (fid < CHUNK && s + 2 < kS) ? 1.f : 0.f;

    float* ldsw = lds;
    const float* ldsr = ldsw + lane * LROW;          // own row
    const float* ldsp = ldsw + (lane ^ 1) * LROW;    // partner row

    float loss = 0.f;

    // ---- stage phase 0 (joints 0..5), prologue j0/j1 ----
    stage<18>(pred, targ, rowbase, s0, 0, ldsw, lane);

    { // joint 0: root channels 0..2; positions identically 0
        float d0 = ldsr[0] - ldsp[0];
        float d1 = ldsr[1] - ldsp[1];
        float d2 = ldsr[2] - ldsp[2];
        loss += wf * (K_R1 * (d0*d0 + d1*d1 + d2*d2));
    }

    float R1s[3][3], p1s[3], R3s[3][3], p3s[3];
    float Rc[3][3], pc[3];              // carried parent rotation / position

    { // joint 1: parent identity; pos = offs[1] for both (pos losses cancel)
        float a_[6], ap_[6];
        read6(ldsr, 1, a_); read6(ldsp, 1, ap_);
        float dsum = 0.f;
        #pragma unroll
        for (int k = 0; k < 6; ++k) { float d = a_[k] - ap_[k]; dsum += d*d; }
        loss += wf * (K_R2 * dsum);
        cont6d(a_, R1s);
        p1s[0] = offs[3]; p1s[1] = offs[4]; p1s[2] = offs[5];
    }
    cp9(R1s, Rc);                       // i=2 parent is joint 1
    pc[0]=p1s[0]; pc[1]=p1s[1]; pc[2]=p1s[2];

    #pragma clang loop unroll(disable)
    for (int i = 2; i < 22; ++i) {
        // phase staging at joint-phase boundaries (uniform branches)
        if (i == 6 || i == 12) {
            asm volatile("s_waitcnt lgkmcnt(0)" ::: "memory");
            stage<18>(pred, targ, rowbase, s0, 6 * i, ldsw, lane);
        } else if (i == 18) {
            asm volatile("s_waitcnt lgkmcnt(0)" ::: "memory");
            stage<12>(pred, targ, rowbase, s0, 108, ldsw, lane);
        }

        // parent restore (uniform): {14,19}->R1 (2 handled by init), {6,10}->R3
        if (i == 14 || i == 19) {
            cp9(R1s, Rc); pc[0]=p1s[0]; pc[1]=p1s[1]; pc[2]=p1s[2];
        } else if (i == 6 || i == 10) {
            cp9(R3s, Rc); pc[0]=p3s[0]; pc[1]=p3s[1]; pc[2]=p3s[2];
        }

        const int jj = i % 6;           // row within current phase
        float a_[6], ap_[6];
        read6(ldsr, jj, a_); read6(ldsp, jj, ap_);

        // raw-channel loss
        float dsum = 0.f;
        #pragma unroll
        for (int k = 0; k < 6; ++k) { float d = a_[k] - ap_[k]; dsum += d*d; }
        loss += wf * (K_ROT * dsum);

        // position uses PARENT rotation
        const float ox = offs[3*i], oy = offs[3*i+1], oz = offs[3*i+2];
        float pn[3];
        #pragma unroll
        for (int r = 0; r < 3; ++r)
            pn[r] = pc[r] + Rc[r][0]*ox + Rc[r][1]*oy + Rc[r][2]*oz;

        // rotation update (skipped for leaves; next iter always restores)
        const bool leaf = (i==5) | (i==9) | (i==13) | (i==18) | (i==21);
        if (!leaf) {
            float Rl[3][3];
            cont6d(a_, Rl);
            if (i == 2) { // spine tilt: local b2 column
                float t0 = Rl[0][1] - __shfl_xor(Rl[0][1], 1);
                float t1 = Rl[1][1] - __shfl_xor(Rl[1][1], 1);
                float t2 = Rl[2][1] - __shfl_xor(Rl[2][1], 1);
                loss += wf * (K_TIL * (t0*t0 + t1*t1 + t2*t2));
            }
            float Rn[3][3];
            #pragma unroll
            for (int r = 0; r < 3; ++r)
                #pragma unroll
                for (int c = 0; c < 3; ++c)
                    Rn[r][c] = Rc[r][0]*Rl[0][c] + Rc[r][1]*Rl[1][c] + Rc[r][2]*Rl[2][c];
            cp9(Rn, Rc);
        }

        // pos / vel / smooth (partner at lane^1; s+1 at lane+2, s+2 at lane+4)
        float d[3];
        #pragma unroll
        for (int r = 0; r < 3; ++r) d[r] = pn[r] - __shfl_xor(pn[r], 1);
        loss += wf * (K_POS * (d[0]*d[0] + d[1]*d[1] + d[2]*d[2]));

        float va = 0.f, sa = 0.f;
        #pragma unroll
        for (int r = 0; r < 3; ++r) {
            float d1 = __shfl_down(d[r], 2);
            float d2 = __shfl_down(d[r], 4);
            float dv = d1 - d[r];            va += dv*dv;
            float ds = d2 - 2.f*d1 + d[r];   sa += ds*ds;
        }
        loss += wv * (K_VEL * va);
        loss += wa * (K_SMO * sa);

        if (i == 18 || i == 21) { // feet: floor + contact
            loss += wf * (K_FLO * (d[1]*d[1]));
            float vx = __shfl_down(pn[0], 2) - pn[0];
            float vy = __shfl_down(pn[1], 2) - pn[1];
            float vz = __shfl_down(pn[2], 2) - pn[2];
            float gx = __shfl_xor(vx, 1);
            float gy = __shfl_xor(vy, 1);
            float gz = __shfl_xor(vz, 1);
            float planted = (gx*gx + gy*gy + gz*gz < 2.5e-5f) ? 1.f : 0.f;
            float wc = (par == 0) ? wv : 0.f;
            loss += wc * (K_CON * (planted * sqrtf(vx*vx + vy*vy + vz*vz)));
        }

        if (i == 3) { // save j3 global state for later subtrees
            cp9(Rc, R3s); p3s[0]=pn[0]; p3s[1]=pn[1]; p3s[2]=pn[2];
        }

        pc[0]=pn[0]; pc[1]=pn[1]; pc[2]=pn[2];   // carry position
    }

    // wave butterfly reduce; one atomic per wave, spread over 64 slots
    float v = loss;
    #pragma unroll
    for (int o = 32; o > 0; o >>= 1) v += __shfl_xor(v, o);
    if (lane == 0) atomicAdd(&acc[cg & (NSLOT - 1)], v);
}

__global__ void finalize_kernel(const float* __restrict__ acc, float* __restrict__ out) {
    float v = acc[threadIdx.x];
    #pragma unroll
    for (int o = 32; o > 0; o >>= 1) v += __shfl_xor(v, o);
    if (threadIdx.x == 0) out[0] = v;
}

} // namespace

extern "C" void kernel_launch(void* const* d_in, const int* in_sizes, int n_in,
                              void* d_out, int out_size, void* d_ws, size_t ws_size,
                              hipStream_t stream) {
    const float* pred = (const float*)d_in[0];
    const float* targ = (const float*)d_in[1];
    const float* offs = (const float*)d_in[2];
    float* acc = (float*)d_ws;

    hipMemsetAsync(acc, 0, NSLOT * sizeof(float), stream);
    motion_loss_kernel<<<dim3(kB * NCHUNK), dim3(64), 0, stream>>>(pred, targ, offs, acc);
    finalize_kernel<<<1, 64, 0, stream>>>(acc, (float*)d_out);
}